// Round 21
// baseline (179.431 us; speedup 1.0000x reference)
//
#include <hip/hip_runtime.h>
#include <hip/hip_bf16.h>

// Problem constants
#define B_ 4
#define S_ 2048
#define D_ 1024
#define H_ 16
#define HD_ 64
#define M_ 8192           // B*S
#define NEGV -1000000.0f
#define CEXP 0.18033688011112042f   // (1/sqrt(HD)) * log2(e) — folded into Q projection

typedef __attribute__((ext_vector_type(8))) __bf16 bf16x8;
typedef __attribute__((ext_vector_type(4))) float f32x4;
typedef __attribute__((ext_vector_type(16))) float f32x16;

__device__ __forceinline__ f32x4 mfma16(bf16x8 a, bf16x8 b, f32x4 c) {
  return __builtin_amdgcn_mfma_f32_16x16x32_bf16(a, b, c, 0, 0, 0);
}
__device__ __forceinline__ f32x16 mfma32(bf16x8 a, bf16x8 b, f32x16 c) {
  return __builtin_amdgcn_mfma_f32_32x32x16_bf16(a, b, c, 0, 0, 0);
}

// raw v_exp_f32 (exp2f without -ffast-math is a guarded libm sequence)
#if __has_builtin(__builtin_amdgcn_exp2f)
__device__ __forceinline__ float exp2_hw(float x) { return __builtin_amdgcn_exp2f(x); }
#else
__device__ __forceinline__ float exp2_hw(float x) {
  float r;
  asm volatile("v_exp_f32 %0, %1" : "=v"(r) : "v"(x));
  return r;
}
#endif

// Branchless RNE fp32->bf16 (exact for all finite values; no NaNs in this pipeline).
__device__ __forceinline__ unsigned bf16rz(float x) {
  unsigned u = __float_as_uint(x);
  return (u + 0x7FFFu + ((u >> 16) & 1u)) >> 16;
}
// pack two floats -> bf16x2 word (lo = a, hi = b)
__device__ __forceinline__ unsigned pk2bf(float a, float b) {
  unsigned ua = __float_as_uint(a), ub = __float_as_uint(b);
  ua = ua + 0x7FFFu + ((ua >> 16) & 1u);
  ub = ub + 0x7FFFu + ((ub >> 16) & 1u);
  return (ua >> 16) | (ub & 0xFFFF0000u);
}

// async global->LDS, 16B per lane. LDS dest is wave-uniform base (HW adds lane*16).
__device__ __forceinline__ void gld_lds16(const __hip_bfloat16* g, __hip_bfloat16* l) {
  __builtin_amdgcn_global_load_lds(
      (const __attribute__((address_space(1))) void*)g,
      (__attribute__((address_space(3))) void*)l, 16, 0, 0);
}

// ---------------- fp32 -> bf16 convert, all three X tensors in one launch -------------
__global__ __launch_bounds__(256) void convert_x3(const float* __restrict__ Xq,
                                                  const float* __restrict__ Xk,
                                                  const float* __restrict__ Xv,
                                                  __hip_bfloat16* __restrict__ Yq,
                                                  __hip_bfloat16* __restrict__ Yk,
                                                  __hip_bfloat16* __restrict__ Yv,
                                                  int n4, const int* __restrict__ vl) {
  const int z = blockIdx.y;
  const float* X = (z == 0) ? Xq : (z == 1) ? Xk : Xv;
  __hip_bfloat16* Y = (z == 0) ? Yq : (z == 1) ? Yk : Yv;
  int i = blockIdx.x * blockDim.x + threadIdx.x;
  if (i >= n4) return;
  if (z) {
    int gm = i >> 8;  // 256 float4 per 1024-wide row
    int vlen = vl[gm >> 11];
    if (vlen > 0 && (gm & 2047) >= ((vlen + 63) & ~63)) return;
  }
  float4 v = reinterpret_cast<const float4*>(X)[i];
  uint2 o;
  o.x = pk2bf(v.x, v.y);
  o.y = pk2bf(v.z, v.w);
  reinterpret_cast<uint2*>(Y)[i] = o;
}

// ---------------- 4x W[1024][1024] fp32 -> W^T bf16 (fused via blockIdx.z) -----------
__global__ __launch_bounds__(256) void convert_wt4(const float* __restrict__ W0,
                                                   const float* __restrict__ W1,
                                                   const float* __restrict__ W2,
                                                   const float* __restrict__ W3,
                                                   __hip_bfloat16* __restrict__ WtBase) {
  const int z = blockIdx.z;
  const float* W = (z == 0) ? W0 : (z == 1) ? W1 : (z == 2) ? W2 : W3;
  __hip_bfloat16* Wt = WtBase + (size_t)z * D_ * D_;
  __shared__ float tile[32][33];
  int c0 = blockIdx.x * 32, r0 = blockIdx.y * 32;
  int tx = threadIdx.x, ty = threadIdx.y;
#pragma unroll
  for (int rr = ty; rr < 32; rr += 8)
    tile[rr][tx] = W[(size_t)(r0 + rr) * D_ + c0 + tx];
  __syncthreads();
#pragma unroll
  for (int rr = ty; rr < 32; rr += 8)
    reinterpret_cast<unsigned short*>(Wt)[(size_t)(c0 + rr) * D_ + r0 + tx] =
        (unsigned short)bf16rz(tile[tx][rr]);
}

// ---------------- GEMM: C[M,N] = A[M,K] * Bt[N,K]^T  (bf16 in, templated epilogue) ----
// BK=64, XOR-swizzled LDS (T2), double-buffered 2-phase schedule (R9-R20-validated).
// LDS invariant: LDS[row][g] = global[row][g ^ (row&7)] (16B granules, involution).
template <int EPI>
__global__ __launch_bounds__(256) void gemm_bt(const __hip_bfloat16* __restrict__ A,
                                               const __hip_bfloat16* __restrict__ Bt,
                                               void* __restrict__ Cout,
                                               const int* __restrict__ vskip,
                                               float cscale) {
  int id = blockIdx.y * gridDim.x + blockIdx.x;
  int cpx = (gridDim.x * gridDim.y) >> 3;
  int nid = (id & 7) * cpx + (id >> 3);
  const int m0 = (nid >> 3) * 128, n0 = (nid & 7) * 128;
  if (vskip) {
    int vlen = vskip[m0 >> 11];
    if (vlen > 0 && (m0 & 2047) >= ((vlen + 63) & ~63)) return;
  }
  const int t = threadIdx.x, lane = t & 63, wid = t >> 6;
  const int lc = lane & 15, g = lane >> 4;
  const int srow8 = lane >> 3, sg8 = lane & 7;
  __shared__ __align__(16) __hip_bfloat16 smem[2][2][128 * 64];  // [buf][A/B][tile] 64KB
  f32x4 acc[4][4] = {};
  const int wm = (wid & 1) * 64, wn = (wid >> 1) * 64;

  auto stage = [&](int buf, int k0) {
#pragma unroll
    for (int c = 0; c < 4; ++c) {
      int ci = c * 4 + wid;              // 1KB chunk index (8 rows)
      int row = ci * 8 + srow8;          // this lane's source row
      int sg = sg8 ^ (row & 7);          // inverse-swizzled source granule
      gld_lds16(A + (size_t)(m0 + row) * D_ + k0 + sg * 8, &smem[buf][0][ci * 512]);
      gld_lds16(Bt + (size_t)(n0 + row) * D_ + k0 + sg * 8, &smem[buf][1][ci * 512]);
    }
  };

  stage(0, 0);
  asm volatile("s_waitcnt vmcnt(0)" ::: "memory");
  __syncthreads();
  int cur = 0;

  for (int kt = 0; kt < D_ / 64; ++kt) {
    if (kt + 1 < D_ / 64) stage(cur ^ 1, (kt + 1) * 64);  // prefetch overlaps compute
    const __hip_bfloat16* As = smem[cur][0];
    const __hip_bfloat16* Bs = smem[cur][1];
#pragma unroll
    for (int kh = 0; kh < 2; ++kh) {  // two K=32 halves of the K=64 tile
      bf16x8 af[4], bf[4];
#pragma unroll
      for (int mi = 0; mi < 4; ++mi) {
        int r = wm + mi * 16 + lc;
        af[mi] = *reinterpret_cast<const bf16x8*>(
            As + r * 64 + (((kh * 4 + g) ^ (r & 7)) << 3));
        int rn = wn + mi * 16 + lc;
        bf[mi] = *reinterpret_cast<const bf16x8*>(
            Bs + rn * 64 + (((kh * 4 + g) ^ (rn & 7)) << 3));
      }
#pragma unroll
      for (int mi = 0; mi < 4; ++mi)
#pragma unroll
        for (int ni = 0; ni < 4; ++ni)
          acc[mi][ni] = mfma16(af[mi], bf[ni], acc[mi][ni]);
    }
    asm volatile("s_waitcnt vmcnt(0)" ::: "memory");
    __syncthreads();
    cur ^= 1;
  }

#pragma unroll
  for (int mi = 0; mi < 4; ++mi) {
#pragma unroll
    for (int ni = 0; ni < 4; ++ni) {
#pragma unroll
      for (int i = 0; i < 4; ++i) {
        int gm = m0 + wm + mi * 16 + g * 4 + i;
        int gn = n0 + wn + ni * 16 + lc;
        float val = acc[mi][ni][i] * cscale;
        if constexpr (EPI == 0) {
          int b = gm >> 11, s = gm & 2047, h = gn >> 6, d = gn & 63;
          reinterpret_cast<unsigned short*>(
              Cout)[(((size_t)(b * H_ + h) * S_ + s) << 6) + d] =
              (unsigned short)bf16rz(val);
        } else if constexpr (EPI == 1) {
          int b = gm >> 11, s = gm & 2047, h = gn >> 6, d = gn & 63;
          reinterpret_cast<unsigned short*>(
              Cout)[(((size_t)(b * H_ + h) * HD_ + d) << 11) + s] =
              (unsigned short)bf16rz(val);
        } else {
          ((float*)Cout)[(size_t)gm * D_ + gn] = val;
        }
      }
    }
  }
}

// ---------------- Flash attention: 8-wave blocks, 2 KV tiles per barrier step ---------
// R20 body verbatim. One change: XCD-aware unit remap — all 8 q-pair blocks of a
// given (b,h) share u mod 8 (the XCD assignment heuristic), so each XCD's K/V
// working set is exactly 8 bh x 512KB = 4MB = its L2. Bijection:
//   bh = (u>>6)*8 + (u&7), qtp = (u>>3)&7.
__global__ __launch_bounds__(512) void attn(const __hip_bfloat16* __restrict__ Qh,
                                            const __hip_bfloat16* __restrict__ Kh,
                                            const __hip_bfloat16* __restrict__ Vt,
                                            const int* __restrict__ vlens,
                                            __hip_bfloat16* __restrict__ O) {
  const int t = threadIdx.x, lane = t & 63, w = t >> 6;  // w in 0..7
  const int wq = w & 3, up = w >> 2;  // sub-wave row group, unit half
  const int q = lane & 31;   // q-row owned by this lane
  const int hh = lane >> 5;  // half-wave

  const int u = blockIdx.x;            // 512 units, all resident from t=0
  const int bh = ((u >> 6) << 3) | (u & 7);  // XCD-grouped: u%8 fixed per bh
  const int qtp = (u >> 3) & 7;        // 256-row q-pair
  const int b = bh >> 4, h = bh & 15;
  const int vlen = vlens[b];

  // two pair-buffers; each holds 2 tiles of [K 64x64 (8KB) | V^T 64x64 (8KB)]
  __shared__ __align__(16) __hip_bfloat16 smem[2][16384];  // 64 KB

  const __hip_bfloat16* Qb = Qh + (size_t)bh * S_ * HD_;
  const __hip_bfloat16* Kb = Kh + (size_t)bh * S_ * HD_;
  const __hip_bfloat16* Vb = Vt + (size_t)bh * HD_ * S_;

  const int qrow = qtp * 256 + up * 128 + wq * 32 + q;
  bf16x8 qf[4];
#pragma unroll
  for (int kk = 0; kk < 4; ++kk)
    qf[kk] = *reinterpret_cast<const bf16x8*>(Qb + (size_t)qrow * HD_ + kk * 16 + hh * 8);

  f32x16 accT[2] = {};  // O^T: accT[ctd] reg r -> d = ctd*32+(r&3)+8*(r>>2)+4*hh, col=q
  float l_half = 0.f;

  const int srow = lane >> 3;  // 0..7
  const int sg = lane & 7;     // 16B granule in 128B row
  const float maskv = (vlen == 0) ? 0.f : NEGV;
  const int kv_end = (vlen == 0) ? S_ : min(S_, (vlen + 63) & ~63);
  const int nt = kv_end >> 6;
  const int npair = (nt + 1) >> 1;

  // stage a PAIR of tiles into buffer buf; wave w stages rows [w*8, w*8+8) of
  // each tile's K and V^T -> up to 4 gld_lds per wave per pair.
  auto stagePair = [&](int buf, int pt) {
    int rr = w * 8 + srow;
    int gs = sg ^ (rr & 7);
#pragma unroll
    for (int half = 0; half < 2; ++half) {
      int tile = 2 * pt + half;
      if (tile >= nt) break;  // odd-nt tail (wave-uniform)
      int kv = tile * 64;
      gld_lds16(Kb + (size_t)(kv + rr) * HD_ + gs * 8,
                smem[buf] + half * 8192 + (w * 8) * 64);
      gld_lds16(Vb + (size_t)rr * S_ + kv + gs * 8,
                smem[buf] + half * 8192 + 4096 + (w * 8) * 64);
    }
  };

  stagePair(0, 0);
  asm volatile("s_waitcnt vmcnt(0)" ::: "memory");
  __syncthreads();
  int cur = 0;

  for (int p = 0; p < npair; ++p) {
    if (p + 1 < npair) stagePair(cur ^ 1, p + 1);  // prefetch overlaps 2-tile compute

#pragma unroll
    for (int half = 0; half < 2; ++half) {
      int tile = 2 * p + half;
      if (tile >= nt) break;  // odd-nt tail (wave-uniform)
      const __hip_bfloat16* Ks = smem[cur] + half * 8192;
      const __hip_bfloat16* Vs = Ks + 4096;

      // S^T tiles (log2-domain scores; Q carried the 0.125*log2e scale)
      f32x16 sc[2];
#pragma unroll
      for (int ct = 0; ct < 2; ++ct) {
        f32x16 a = {};
#pragma unroll
        for (int kk = 0; kk < 4; ++kk) {
          int row = ct * 32 + q;
          bf16x8 kf = *reinterpret_cast<const bf16x8*>(
              Ks + row * 64 + (((kk * 2 + hh) ^ (row & 7)) << 3));
          a = mfma32(kf, qf[kk], a);
        }
        sc[ct] = a;
      }

      // padding mask (boundary tile only; wave-uniform branch)
      int kv = tile * 64;
      if (kv + 64 > vlen) {
#pragma unroll
        for (int ct = 0; ct < 2; ++ct)
#pragma unroll
          for (int rr = 0; rr < 16; ++rr) {
            int j = kv + ct * 32 + (rr & 3) + 8 * (rr >> 2) + 4 * hh;
            if (j >= vlen) sc[ct][rr] = maskv;
          }
      }

      // exp (raw v_exp_f32) + bit-trick pack into 16 bf16x2 words
      uint wlo[8], whi[8];
      float rs = 0.f;
#pragma unroll
      for (int a2 = 0; a2 < 8; ++a2) {
        float p0 = exp2_hw(sc[a2 >> 2][(a2 & 3) * 4 + 0]);
        float p1 = exp2_hw(sc[a2 >> 2][(a2 & 3) * 4 + 1]);
        float p2 = exp2_hw(sc[a2 >> 2][(a2 & 3) * 4 + 2]);
        float p3 = exp2_hw(sc[a2 >> 2][(a2 & 3) * 4 + 3]);
        rs += (p0 + p1) + (p2 + p3);
        wlo[a2] = pk2bf(p0, p1);
        whi[a2] = pk2bf(p2, p3);
      }
      l_half += rs;

      // PV: B-frag = P[q][kk*16 + hh*8 + i]; half-wave exchange fills missing slots
#pragma unroll
      for (int kk = 0; kk < 4; ++kk) {
        uint glo = wlo[2 * kk], ghi = whi[2 * kk];
        uint flo = wlo[2 * kk + 1], fhi = whi[2 * kk + 1];
        uint slo = hh ? glo : flo, shi = hh ? ghi : fhi;
        uint rlo = __shfl_xor(slo, 32), rhi = __shfl_xor(shi, 32);
        union { uint u[4]; bf16x8 v; } pf;
        pf.u[0] = hh ? rlo : glo;
        pf.u[1] = hh ? rhi : ghi;
        pf.u[2] = hh ? flo : rlo;
        pf.u[3] = hh ? fhi : rhi;
#pragma unroll
        for (int ctd = 0; ctd < 2; ++ctd) {
          int vr = ctd * 32 + q;
          bf16x8 vf = *reinterpret_cast<const bf16x8*>(
              Vs + vr * 64 + (((kk * 2 + hh) ^ (vr & 7)) << 3));
          accT[ctd] = mfma32(vf, pf.v, accT[ctd]);
        }
      }
    }

    // drain own prefetch (issued before the 2-tile compute, so HBM latency is
    // covered) + barrier: all waves' stage(p+1) writes visible, buffer safe.
    asm volatile("s_waitcnt vmcnt(0)" ::: "memory");
    __syncthreads();
    cur ^= 1;
  }

  // epilogue: O^T -> O via per-wave LDS transpose (same-wave ordering, no barrier).
  // 8 waves x 4KB = 32KB fits pair buffer 0 (loop-end barrier protects it).
  float l_tot = l_half + __shfl_xor(l_half, 32);
  float inv = 1.f / l_tot;
  __hip_bfloat16* Ot = smem[0] + w * 2048;  // [32 q][64 d], 8B-granule swizzle
#pragma unroll
  for (int ctd = 0; ctd < 2; ++ctd)
#pragma unroll
    for (int a2 = 0; a2 < 4; ++a2) {
      uint2 o;
      o.x = pk2bf(accT[ctd][a2 * 4 + 0] * inv, accT[ctd][a2 * 4 + 1] * inv);
      o.y = pk2bf(accT[ctd][a2 * 4 + 2] * inv, accT[ctd][a2 * 4 + 3] * inv);
      int gs8 = (ctd * 8 + a2 * 2 + hh) ^ ((q & 7) << 1);
      *reinterpret_cast<uint2*>(Ot + q * 64 + gs8 * 4) = o;
    }
#pragma unroll
  for (int rr = 0; rr < 4; ++rr) {
    int row = rr * 8 + (lane >> 3);  // q-row within wave tile
    int c16 = lane & 7;              // 16B chunk of d
    float4 v4 = *reinterpret_cast<const float4*>(
        Ot + row * 64 + (((c16 * 2) ^ ((row & 7) << 1)) << 2));
    int s = qtp * 256 + up * 128 + wq * 32 + row;
    *reinterpret_cast<float4*>(O + ((size_t)b * S_ + s) * D_ + h * HD_ + c16 * 8) = v4;
  }
}

extern "C" void kernel_launch(void* const* d_in, const int* in_sizes, int n_in,
                              void* d_out, int out_size, void* d_ws, size_t ws_size,
                              hipStream_t stream) {
  const float* Xq = (const float*)d_in[0];
  const float* Xk = (const float*)d_in[1];
  const float* Xv = (const float*)d_in[2];
  const int* vl = (const int*)d_in[3];
  const float* Wq = (const float*)d_in[4];
  const float* Wk = (const float*)d_in[5];
  const float* Wv = (const float*)d_in[6];
  const float* Wo = (const float*)d_in[7];
  float* out = (float*)d_out;

  char* ws = (char*)d_ws;
  const size_t XB = (size_t)M_ * D_ * 2;   // 16 MB bf16 [8192][1024]
  const size_t WB = (size_t)D_ * D_ * 2;   // 2 MB bf16 [1024][1024]
  __hip_bfloat16* xq = (__hip_bfloat16*)(ws);                    // Xq bf16, later Obuf
  __hip_bfloat16* xk = (__hip_bfloat16*)(ws + XB);               // Xk bf16
  __hip_bfloat16* xv = (__hip_bfloat16*)(ws + 2 * XB);           // Xv bf16
  __hip_bfloat16* wtq = (__hip_bfloat16*)(ws + 3 * XB);          // wtq..wto contiguous
  __hip_bfloat16* wtk = (__hip_bfloat16*)(ws + 3 * XB + WB);
  __hip_bfloat16* wtv = (__hip_bfloat16*)(ws + 3 * XB + 2 * WB);
  __hip_bfloat16* wto = (__hip_bfloat16*)(ws + 3 * XB + 3 * WB);
  __hip_bfloat16* Qh = (__hip_bfloat16*)(ws + 3 * XB + 4 * WB);      // [B][H][S][HD]
  __hip_bfloat16* Kh = (__hip_bfloat16*)(ws + 4 * XB + 4 * WB);      // [B][H][S][HD]
  __hip_bfloat16* Vh = (__hip_bfloat16*)(ws + 5 * XB + 4 * WB);      // [B][H][HD][S]
  __hip_bfloat16* Obuf = xq;      // alias: xq dead after the Q projection GEMM

  convert_wt4<<<dim3(32, 32, 4), dim3(32, 8), 0, stream>>>(Wq, Wk, Wv, Wo, wtq);

  const int n4 = M_ * D_ / 4;
  convert_x3<<<dim3(n4 / 256, 3), 256, 0, stream>>>(Xq, Xk, Xv, xq, xk, xv, n4, vl);

  dim3 gg(M_ / 128, D_ / 128);
  gemm_bt<0><<<gg, 256, 0, stream>>>(xq, wtq, Qh, nullptr, CEXP);  // Q carries softmax scale
  gemm_bt<0><<<gg, 256, 0, stream>>>(xk, wtk, Kh, vl, 1.0f);
  gemm_bt<1><<<gg, 256, 0, stream>>>(xv, wtv, Vh, vl, 1.0f);

  attn<<<dim3(512), 512, 0, stream>>>(Qh, Kh, Vh, vl, Obuf);
  gemm_bt<2><<<gg, 256, 0, stream>>>(Obuf, wto, out, nullptr, 1.0f);
}

// Round 22
// 174.958 us; speedup vs baseline: 1.0256x; 1.0256x over previous
//
#include <hip/hip_runtime.h>
#include <hip/hip_bf16.h>

// Problem constants
#define B_ 4
#define S_ 2048
#define D_ 1024
#define H_ 16
#define HD_ 64
#define M_ 8192           // B*S
#define NEGV -1000000.0f
#define CEXP 0.18033688011112042f   // (1/sqrt(HD)) * log2(e) — folded into Q projection

typedef __attribute__((ext_vector_type(8))) __bf16 bf16x8;
typedef __attribute__((ext_vector_type(4))) float f32x4;
typedef __attribute__((ext_vector_type(16))) float f32x16;

__device__ __forceinline__ f32x4 mfma16(bf16x8 a, bf16x8 b, f32x4 c) {
  return __builtin_amdgcn_mfma_f32_16x16x32_bf16(a, b, c, 0, 0, 0);
}
__device__ __forceinline__ f32x16 mfma32(bf16x8 a, bf16x8 b, f32x16 c) {
  return __builtin_amdgcn_mfma_f32_32x32x16_bf16(a, b, c, 0, 0, 0);
}

// raw v_exp_f32 (exp2f without -ffast-math is a guarded libm sequence)
#if __has_builtin(__builtin_amdgcn_exp2f)
__device__ __forceinline__ float exp2_hw(float x) { return __builtin_amdgcn_exp2f(x); }
#else
__device__ __forceinline__ float exp2_hw(float x) {
  float r;
  asm volatile("v_exp_f32 %0, %1" : "=v"(r) : "v"(x));
  return r;
}
#endif

// Branchless RNE fp32->bf16 (exact for all finite values; no NaNs in this pipeline).
__device__ __forceinline__ unsigned bf16rz(float x) {
  unsigned u = __float_as_uint(x);
  return (u + 0x7FFFu + ((u >> 16) & 1u)) >> 16;
}
// pack two floats -> bf16x2 word (lo = a, hi = b)
__device__ __forceinline__ unsigned pk2bf(float a, float b) {
  unsigned ua = __float_as_uint(a), ub = __float_as_uint(b);
  ua = ua + 0x7FFFu + ((ua >> 16) & 1u);
  ub = ub + 0x7FFFu + ((ub >> 16) & 1u);
  return (ua >> 16) | (ub & 0xFFFF0000u);
}

// async global->LDS, 16B per lane. LDS dest is wave-uniform base (HW adds lane*16).
__device__ __forceinline__ void gld_lds16(const __hip_bfloat16* g, __hip_bfloat16* l) {
  __builtin_amdgcn_global_load_lds(
      (const __attribute__((address_space(1))) void*)g,
      (__attribute__((address_space(3))) void*)l, 16, 0, 0);
}

// ---------------- fused convert: 3x X fp32->bf16 + 4x W fp32->W^T bf16, one launch ----
// 1D grid of 24576+4096 blocks, 256 threads. Block-uniform path select:
//   id < 24576: X convert (z = id>>13, 8192 blocks each; K/V rows vskip'd)
//   else:       weight transpose (z = (id-24576)>>10; 32x32 tile per block)
__global__ __launch_bounds__(256) void convert_all(const float* __restrict__ Xq,
                                                   const float* __restrict__ Xk,
                                                   const float* __restrict__ Xv,
                                                   __hip_bfloat16* __restrict__ Yq,
                                                   __hip_bfloat16* __restrict__ Yk,
                                                   __hip_bfloat16* __restrict__ Yv,
                                                   const float* __restrict__ W0,
                                                   const float* __restrict__ W1,
                                                   const float* __restrict__ W2,
                                                   const float* __restrict__ W3,
                                                   __hip_bfloat16* __restrict__ WtBase,
                                                   const int* __restrict__ vl) {
  const int id = blockIdx.x, tid = threadIdx.x;
  if (id < 24576) {
    const int z = id >> 13;            // 8192 blocks per tensor (n4 = 2M/256 = 8192)
    const float* X = (z == 0) ? Xq : (z == 1) ? Xk : Xv;
    __hip_bfloat16* Y = (z == 0) ? Yq : (z == 1) ? Yk : Yv;
    int i = (id & 8191) * 256 + tid;
    if (z) {
      int gm = i >> 8;  // 256 float4 per 1024-wide row
      int vlen = vl[gm >> 11];
      if (vlen > 0 && (gm & 2047) >= ((vlen + 63) & ~63)) return;
    }
    float4 v = reinterpret_cast<const float4*>(X)[i];
    uint2 o;
    o.x = pk2bf(v.x, v.y);
    o.y = pk2bf(v.z, v.w);
    reinterpret_cast<uint2*>(Y)[i] = o;
  } else {
    const int wid = id - 24576;
    const int z = wid >> 10;           // 1024 blocks per weight (32x32 tiles)
    const float* W = (z == 0) ? W0 : (z == 1) ? W1 : (z == 2) ? W2 : W3;
    __hip_bfloat16* Wt = WtBase + (size_t)z * D_ * D_;
    const int t10 = wid & 1023;
    const int c0 = (t10 & 31) * 32, r0 = (t10 >> 5) * 32;
    const int tx = tid & 31, ty = tid >> 5;  // 32x8 layout
    __shared__ float tile[32][33];
#pragma unroll
    for (int rr = ty; rr < 32; rr += 8)
      tile[rr][tx] = W[(size_t)(r0 + rr) * D_ + c0 + tx];
    __syncthreads();
#pragma unroll
    for (int rr = ty; rr < 32; rr += 8)
      reinterpret_cast<unsigned short*>(Wt)[(size_t)(c0 + rr) * D_ + r0 + tx] =
          (unsigned short)bf16rz(tile[tx][rr]);
  }
}

// ---------------- GEMM: C[M,N] = A[M,K] * Bt[N,K]^T  (bf16 in, templated epilogue) ----
// BK=64, XOR-swizzled LDS (T2), double-buffered 2-phase schedule (R9-R21-validated).
// LDS invariant: LDS[row][g] = global[row][g ^ (row&7)] (16B granules, involution).
template <int EPI>
__global__ __launch_bounds__(256) void gemm_bt(const __hip_bfloat16* __restrict__ A,
                                               const __hip_bfloat16* __restrict__ Bt,
                                               void* __restrict__ Cout,
                                               const int* __restrict__ vskip,
                                               float cscale) {
  int id = blockIdx.y * gridDim.x + blockIdx.x;
  int cpx = (gridDim.x * gridDim.y) >> 3;
  int nid = (id & 7) * cpx + (id >> 3);
  const int m0 = (nid >> 3) * 128, n0 = (nid & 7) * 128;
  if (vskip) {
    int vlen = vskip[m0 >> 11];
    if (vlen > 0 && (m0 & 2047) >= ((vlen + 63) & ~63)) return;
  }
  const int t = threadIdx.x, lane = t & 63, wid = t >> 6;
  const int lc = lane & 15, g = lane >> 4;
  const int srow8 = lane >> 3, sg8 = lane & 7;
  __shared__ __align__(16) __hip_bfloat16 smem[2][2][128 * 64];  // [buf][A/B][tile] 64KB
  f32x4 acc[4][4] = {};
  const int wm = (wid & 1) * 64, wn = (wid >> 1) * 64;

  auto stage = [&](int buf, int k0) {
#pragma unroll
    for (int c = 0; c < 4; ++c) {
      int ci = c * 4 + wid;              // 1KB chunk index (8 rows)
      int row = ci * 8 + srow8;          // this lane's source row
      int sg = sg8 ^ (row & 7);          // inverse-swizzled source granule
      gld_lds16(A + (size_t)(m0 + row) * D_ + k0 + sg * 8, &smem[buf][0][ci * 512]);
      gld_lds16(Bt + (size_t)(n0 + row) * D_ + k0 + sg * 8, &smem[buf][1][ci * 512]);
    }
  };

  stage(0, 0);
  asm volatile("s_waitcnt vmcnt(0)" ::: "memory");
  __syncthreads();
  int cur = 0;

  for (int kt = 0; kt < D_ / 64; ++kt) {
    if (kt + 1 < D_ / 64) stage(cur ^ 1, (kt + 1) * 64);  // prefetch overlaps compute
    const __hip_bfloat16* As = smem[cur][0];
    const __hip_bfloat16* Bs = smem[cur][1];
#pragma unroll
    for (int kh = 0; kh < 2; ++kh) {  // two K=32 halves of the K=64 tile
      bf16x8 af[4], bf[4];
#pragma unroll
      for (int mi = 0; mi < 4; ++mi) {
        int r = wm + mi * 16 + lc;
        af[mi] = *reinterpret_cast<const bf16x8*>(
            As + r * 64 + (((kh * 4 + g) ^ (r & 7)) << 3));
        int rn = wn + mi * 16 + lc;
        bf[mi] = *reinterpret_cast<const bf16x8*>(
            Bs + rn * 64 + (((kh * 4 + g) ^ (rn & 7)) << 3));
      }
#pragma unroll
      for (int mi = 0; mi < 4; ++mi)
#pragma unroll
        for (int ni = 0; ni < 4; ++ni)
          acc[mi][ni] = mfma16(af[mi], bf[ni], acc[mi][ni]);
    }
    asm volatile("s_waitcnt vmcnt(0)" ::: "memory");
    __syncthreads();
    cur ^= 1;
  }

#pragma unroll
  for (int mi = 0; mi < 4; ++mi) {
#pragma unroll
    for (int ni = 0; ni < 4; ++ni) {
#pragma unroll
      for (int i = 0; i < 4; ++i) {
        int gm = m0 + wm + mi * 16 + g * 4 + i;
        int gn = n0 + wn + ni * 16 + lc;
        float val = acc[mi][ni][i] * cscale;
        if constexpr (EPI == 0) {
          int b = gm >> 11, s = gm & 2047, h = gn >> 6, d = gn & 63;
          reinterpret_cast<unsigned short*>(
              Cout)[(((size_t)(b * H_ + h) * S_ + s) << 6) + d] =
              (unsigned short)bf16rz(val);
        } else if constexpr (EPI == 1) {
          int b = gm >> 11, s = gm & 2047, h = gn >> 6, d = gn & 63;
          reinterpret_cast<unsigned short*>(
              Cout)[(((size_t)(b * H_ + h) * HD_ + d) << 11) + s] =
              (unsigned short)bf16rz(val);
        } else {
          ((float*)Cout)[(size_t)gm * D_ + gn] = val;
        }
      }
    }
  }
}

// ---------------- Flash attention: 8-wave blocks, 2 KV tiles per barrier step ---------
// R20 verbatim (best measured: attn 70.2 us; the R21 XCD remap was neutral — K/V is
// already fully L2/LLC-resident — and is reverted). Static unit = blockIdx.x; 512
// units all resident from t=0 (66KB LDS -> 2 blocks/CU x 256 = 512).
__global__ __launch_bounds__(512) void attn(const __hip_bfloat16* __restrict__ Qh,
                                            const __hip_bfloat16* __restrict__ Kh,
                                            const __hip_bfloat16* __restrict__ Vt,
                                            const int* __restrict__ vlens,
                                            __hip_bfloat16* __restrict__ O) {
  const int t = threadIdx.x, lane = t & 63, w = t >> 6;  // w in 0..7
  const int wq = w & 3, up = w >> 2;  // sub-wave row group, unit half
  const int q = lane & 31;   // q-row owned by this lane
  const int hh = lane >> 5;  // half-wave

  const int u = blockIdx.x;           // 512 units, all resident from t=0
  const int b = u >> 7;               // 128 units per batch
  const int vlen = vlens[b];
  const int r = u & 127;
  const int h = r & 15, qtp = r >> 4; // qtp in 0..7: 256-row q-pair
  const int bh = b * 16 + h;

  // two pair-buffers; each holds 2 tiles of [K 64x64 (8KB) | V^T 64x64 (8KB)]
  __shared__ __align__(16) __hip_bfloat16 smem[2][16384];  // 64 KB

  const __hip_bfloat16* Qb = Qh + (size_t)bh * S_ * HD_;
  const __hip_bfloat16* Kb = Kh + (size_t)bh * S_ * HD_;
  const __hip_bfloat16* Vb = Vt + (size_t)bh * HD_ * S_;

  const int qrow = qtp * 256 + up * 128 + wq * 32 + q;
  bf16x8 qf[4];
#pragma unroll
  for (int kk = 0; kk < 4; ++kk)
    qf[kk] = *reinterpret_cast<const bf16x8*>(Qb + (size_t)qrow * HD_ + kk * 16 + hh * 8);

  f32x16 accT[2] = {};  // O^T: accT[ctd] reg r -> d = ctd*32+(r&3)+8*(r>>2)+4*hh, col=q
  float l_half = 0.f;

  const int srow = lane >> 3;  // 0..7
  const int sg = lane & 7;     // 16B granule in 128B row
  const float maskv = (vlen == 0) ? 0.f : NEGV;
  const int kv_end = (vlen == 0) ? S_ : min(S_, (vlen + 63) & ~63);
  const int nt = kv_end >> 6;
  const int npair = (nt + 1) >> 1;

  // stage a PAIR of tiles into buffer buf; wave w stages rows [w*8, w*8+8) of
  // each tile's K and V^T -> up to 4 gld_lds per wave per pair.
  auto stagePair = [&](int buf, int pt) {
    int rr = w * 8 + srow;
    int gs = sg ^ (rr & 7);
#pragma unroll
    for (int half = 0; half < 2; ++half) {
      int tile = 2 * pt + half;
      if (tile >= nt) break;  // odd-nt tail (wave-uniform)
      int kv = tile * 64;
      gld_lds16(Kb + (size_t)(kv + rr) * HD_ + gs * 8,
                smem[buf] + half * 8192 + (w * 8) * 64);
      gld_lds16(Vb + (size_t)rr * S_ + kv + gs * 8,
                smem[buf] + half * 8192 + 4096 + (w * 8) * 64);
    }
  };

  stagePair(0, 0);
  asm volatile("s_waitcnt vmcnt(0)" ::: "memory");
  __syncthreads();
  int cur = 0;

  for (int p = 0; p < npair; ++p) {
    if (p + 1 < npair) stagePair(cur ^ 1, p + 1);  // prefetch overlaps 2-tile compute

#pragma unroll
    for (int half = 0; half < 2; ++half) {
      int tile = 2 * p + half;
      if (tile >= nt) break;  // odd-nt tail (wave-uniform)
      const __hip_bfloat16* Ks = smem[cur] + half * 8192;
      const __hip_bfloat16* Vs = Ks + 4096;

      // S^T tiles (log2-domain scores; Q carried the 0.125*log2e scale)
      f32x16 sc[2];
#pragma unroll
      for (int ct = 0; ct < 2; ++ct) {
        f32x16 a = {};
#pragma unroll
        for (int kk = 0; kk < 4; ++kk) {
          int row = ct * 32 + q;
          bf16x8 kf = *reinterpret_cast<const bf16x8*>(
              Ks + row * 64 + (((kk * 2 + hh) ^ (row & 7)) << 3));
          a = mfma32(kf, qf[kk], a);
        }
        sc[ct] = a;
      }

      // padding mask (boundary tile only; wave-uniform branch)
      int kv = tile * 64;
      if (kv + 64 > vlen) {
#pragma unroll
        for (int ct = 0; ct < 2; ++ct)
#pragma unroll
          for (int rr = 0; rr < 16; ++rr) {
            int j = kv + ct * 32 + (rr & 3) + 8 * (rr >> 2) + 4 * hh;
            if (j >= vlen) sc[ct][rr] = maskv;
          }
      }

      // exp (raw v_exp_f32) + bit-trick pack into 16 bf16x2 words
      uint wlo[8], whi[8];
      float rs = 0.f;
#pragma unroll
      for (int a2 = 0; a2 < 8; ++a2) {
        float p0 = exp2_hw(sc[a2 >> 2][(a2 & 3) * 4 + 0]);
        float p1 = exp2_hw(sc[a2 >> 2][(a2 & 3) * 4 + 1]);
        float p2 = exp2_hw(sc[a2 >> 2][(a2 & 3) * 4 + 2]);
        float p3 = exp2_hw(sc[a2 >> 2][(a2 & 3) * 4 + 3]);
        rs += (p0 + p1) + (p2 + p3);
        wlo[a2] = pk2bf(p0, p1);
        whi[a2] = pk2bf(p2, p3);
      }
      l_half += rs;

      // PV: B-frag = P[q][kk*16 + hh*8 + i]; half-wave exchange fills missing slots
#pragma unroll
      for (int kk = 0; kk < 4; ++kk) {
        uint glo = wlo[2 * kk], ghi = whi[2 * kk];
        uint flo = wlo[2 * kk + 1], fhi = whi[2 * kk + 1];
        uint slo = hh ? glo : flo, shi = hh ? ghi : fhi;
        uint rlo = __shfl_xor(slo, 32), rhi = __shfl_xor(shi, 32);
        union { uint u[4]; bf16x8 v; } pf;
        pf.u[0] = hh ? rlo : glo;
        pf.u[1] = hh ? rhi : ghi;
        pf.u[2] = hh ? flo : rlo;
        pf.u[3] = hh ? fhi : rhi;
#pragma unroll
        for (int ctd = 0; ctd < 2; ++ctd) {
          int vr = ctd * 32 + q;
          bf16x8 vf = *reinterpret_cast<const bf16x8*>(
              Vs + vr * 64 + (((kk * 2 + hh) ^ (vr & 7)) << 3));
          accT[ctd] = mfma32(vf, pf.v, accT[ctd]);
        }
      }
    }

    // drain own prefetch (issued before the 2-tile compute, so HBM latency is
    // covered) + barrier: all waves' stage(p+1) writes visible, buffer safe.
    asm volatile("s_waitcnt vmcnt(0)" ::: "memory");
    __syncthreads();
    cur ^= 1;
  }

  // epilogue: O^T -> O via per-wave LDS transpose (same-wave ordering, no barrier).
  // 8 waves x 4KB = 32KB fits pair buffer 0 (loop-end barrier protects it).
  float l_tot = l_half + __shfl_xor(l_half, 32);
  float inv = 1.f / l_tot;
  __hip_bfloat16* Ot = smem[0] + w * 2048;  // [32 q][64 d], 8B-granule swizzle
#pragma unroll
  for (int ctd = 0; ctd < 2; ++ctd)
#pragma unroll
    for (int a2 = 0; a2 < 4; ++a2) {
      uint2 o;
      o.x = pk2bf(accT[ctd][a2 * 4 + 0] * inv, accT[ctd][a2 * 4 + 1] * inv);
      o.y = pk2bf(accT[ctd][a2 * 4 + 2] * inv, accT[ctd][a2 * 4 + 3] * inv);
      int gs8 = (ctd * 8 + a2 * 2 + hh) ^ ((q & 7) << 1);
      *reinterpret_cast<uint2*>(Ot + q * 64 + gs8 * 4) = o;
    }
#pragma unroll
  for (int rr = 0; rr < 4; ++rr) {
    int row = rr * 8 + (lane >> 3);  // q-row within wave tile
    int c16 = lane & 7;              // 16B chunk of d
    float4 v4 = *reinterpret_cast<const float4*>(
        Ot + row * 64 + (((c16 * 2) ^ ((row & 7) << 1)) << 2));
    int s = qtp * 256 + up * 128 + wq * 32 + row;
    *reinterpret_cast<float4*>(O + ((size_t)b * S_ + s) * D_ + h * HD_ + c16 * 8) = v4;
  }
}

extern "C" void kernel_launch(void* const* d_in, const int* in_sizes, int n_in,
                              void* d_out, int out_size, void* d_ws, size_t ws_size,
                              hipStream_t stream) {
  const float* Xq = (const float*)d_in[0];
  const float* Xk = (const float*)d_in[1];
  const float* Xv = (const float*)d_in[2];
  const int* vl = (const int*)d_in[3];
  const float* Wq = (const float*)d_in[4];
  const float* Wk = (const float*)d_in[5];
  const float* Wv = (const float*)d_in[6];
  const float* Wo = (const float*)d_in[7];
  float* out = (float*)d_out;

  char* ws = (char*)d_ws;
  const size_t XB = (size_t)M_ * D_ * 2;   // 16 MB bf16 [8192][1024]
  const size_t WB = (size_t)D_ * D_ * 2;   // 2 MB bf16 [1024][1024]
  __hip_bfloat16* xq = (__hip_bfloat16*)(ws);                    // Xq bf16, later Obuf
  __hip_bfloat16* xk = (__hip_bfloat16*)(ws + XB);               // Xk bf16
  __hip_bfloat16* xv = (__hip_bfloat16*)(ws + 2 * XB);           // Xv bf16
  __hip_bfloat16* wtq = (__hip_bfloat16*)(ws + 3 * XB);          // wtq..wto contiguous
  __hip_bfloat16* wtk = (__hip_bfloat16*)(ws + 3 * XB + WB);
  __hip_bfloat16* wtv = (__hip_bfloat16*)(ws + 3 * XB + 2 * WB);
  __hip_bfloat16* wto = (__hip_bfloat16*)(ws + 3 * XB + 3 * WB);
  __hip_bfloat16* Qh = (__hip_bfloat16*)(ws + 3 * XB + 4 * WB);      // [B][H][S][HD]
  __hip_bfloat16* Kh = (__hip_bfloat16*)(ws + 4 * XB + 4 * WB);      // [B][H][S][HD]
  __hip_bfloat16* Vh = (__hip_bfloat16*)(ws + 5 * XB + 4 * WB);      // [B][H][HD][S]
  __hip_bfloat16* Obuf = xq;      // alias: xq dead after the Q projection GEMM

  // single fused convert dispatch: 24576 X-convert blocks + 4096 W-transpose blocks
  convert_all<<<dim3(24576 + 4096), 256, 0, stream>>>(Xq, Xk, Xv, xq, xk, xv,
                                                      Wq, Wk, Wv, Wo, wtq, vl);

  dim3 gg(M_ / 128, D_ / 128);
  gemm_bt<0><<<gg, 256, 0, stream>>>(xq, wtq, Qh, nullptr, CEXP);  // Q carries softmax scale
  gemm_bt<0><<<gg, 256, 0, stream>>>(xk, wtk, Kh, vl, 1.0f);
  gemm_bt<1><<<gg, 256, 0, stream>>>(xv, wtv, Vh, vl, 1.0f);

  attn<<<dim3(512), 512, 0, stream>>>(Qh, Kh, Vh, vl, Obuf);
  gemm_bt<2><<<gg, 256, 0, stream>>>(Obuf, wto, out, nullptr, 1.0f);
}